// Round 2
// baseline (207.095 us; speedup 1.0000x reference)
//
#include <hip/hip_runtime.h>

// Fused Xcodec2 ISTFT: B=16, FREQ=513, FRAMES=2048, n_fft=1024, hop=256, win=1024
// out: [16, 1, 524288] fp32
//
// Single-kernel version:
//  - irfft(1024) via half-size complex inverse FFT (N=512), radix-8 Stockham,
//    3 register butterflies, 2 LDS exchanges (conflict-free odd-stride layout).
//  - All 32 pass-1 global loads batch-issued with an asm keep-alive fence so
//    the compiler keeps them ALL in flight (one vmcnt wait, covered by table
//    gen + barrier). 32-bit offset addressing (base fits SGPR pair, offset
//    fits u32) to cut 64-bit address VALU.
//  - Twiddle tables generated into LDS per-WG with fast __sincosf while the
//    loads are in flight.
//  - Envelope divide uses the exact COLA identity: sum_j hann^2(p+256j) = 1.5,
//    so invenv = 2/3 everywhere except the first/last ~400 samples (computed
//    per-sample in the 2 edge WG columns only). No prep kernel.

#define B_      16
#define FREQ_   513
#define FRAMES_ 2048
#define NFFT_   1024
#define HOP_    256
#define NH_     512
#define PAD_    384
#define T_OUT_  524288
#define HPW     12           // useful hops per WG
#define SPW     3072         // output samples per WG
#define NCHUNK  171          // ceil(T_OUT/SPW)

#define ZSTR2   513          // float2 row stride for Z   (odd -> uniform bank pairs)
#define XWSTR   513          // float row stride for XWe/XWo planes (odd)
#define TWF     16416        // float offset of tw512 table (512 float2)
#define PREF    17440        // float offset of pre  table (512 float2)
#define LDSF    18464        // total floats: 16*513*2 (Z / XWe+XWo overlay) + tables

#define KEEP8(a) asm volatile("" \
  : "+v"(a[0]), "+v"(a[1]), "+v"(a[2]), "+v"(a[3]), \
    "+v"(a[4]), "+v"(a[5]), "+v"(a[6]), "+v"(a[7]))

// 8-point inverse DFT (sign +i), DIF, in-place; output slot r holds y[brev3(r)].
__device__ __forceinline__ void idft8(float* zr, float* zi) {
  const float C = 0.70710678118654752f;
  float tr, ti;
  tr = zr[0]-zr[4]; ti = zi[0]-zi[4]; zr[0]+=zr[4]; zi[0]+=zi[4]; zr[4]=tr;         zi[4]=ti;
  tr = zr[1]-zr[5]; ti = zi[1]-zi[5]; zr[1]+=zr[5]; zi[1]+=zi[5]; zr[5]=C*(tr-ti);  zi[5]=C*(tr+ti);
  tr = zr[2]-zr[6]; ti = zi[2]-zi[6]; zr[2]+=zr[6]; zi[2]+=zi[6]; zr[6]=-ti;        zi[6]=tr;
  tr = zr[3]-zr[7]; ti = zi[3]-zi[7]; zr[3]+=zr[7]; zi[3]+=zi[7]; zr[7]=-C*(tr+ti); zi[7]=C*(tr-ti);
  tr = zr[0]-zr[2]; ti = zi[0]-zi[2]; zr[0]+=zr[2]; zi[0]+=zi[2]; zr[2]=tr;  zi[2]=ti;
  tr = zr[1]-zr[3]; ti = zi[1]-zi[3]; zr[1]+=zr[3]; zi[1]+=zi[3]; zr[3]=-ti; zi[3]=tr;
  tr = zr[4]-zr[6]; ti = zi[4]-zi[6]; zr[4]+=zr[6]; zi[4]+=zi[6]; zr[6]=tr;  zi[6]=ti;
  tr = zr[5]-zr[7]; ti = zi[5]-zi[7]; zr[5]+=zr[7]; zi[5]+=zi[7]; zr[7]=-ti; zi[7]=tr;
  tr = zr[0]-zr[1]; ti = zi[0]-zi[1]; zr[0]+=zr[1]; zi[0]+=zi[1]; zr[1]=tr; zi[1]=ti;
  tr = zr[2]-zr[3]; ti = zi[2]-zi[3]; zr[2]+=zr[3]; zi[2]+=zi[3]; zr[3]=tr; zi[3]=ti;
  tr = zr[4]-zr[5]; ti = zi[4]-zi[5]; zr[4]+=zr[5]; zi[4]+=zi[5]; zr[5]=tr; zi[5]=ti;
  tr = zr[6]-zr[7]; ti = zi[6]-zi[7]; zr[6]+=zr[7]; zi[6]+=zi[7]; zr[7]=tr; zi[7]=ti;
}

__global__ __launch_bounds__(1024, 8) void k_fused(
    const float* __restrict__ sre, const float* __restrict__ sim,
    const float* __restrict__ win, float* __restrict__ out) {
  __shared__ __align__(16) float lds[LDSF];
  float2* __restrict__ Z2  = (float2*)lds;            // [f][i], stride ZSTR2
  float2* __restrict__ TW  = (float2*)(lds + TWF);    // W_512^k, k=0..511
  float2* __restrict__ PRE = (float2*)(lds + PREF);   // e^{+i pi k/512}, k=0..511

  const int t = threadIdx.x;
  const int f = t & 15;                // frame slot (16 consecutive frames/load)
  const int j = t >> 4;                // 0..63 butterfly lane
  const int b   = blockIdx.x & 15;
  const int wgq = blockIdx.x >> 4;
  const int f_base = HPW * wgq - 2;
  const int s0     = SPW * wgq;
  const int fg = f_base + f;
  const bool fv = (fg >= 0) && (fg < FRAMES_);
  const int fgc = fv ? fg : 0;
  const float scale = fv ? (0.5f / 512.0f) : 0.0f;  // 0.5 (E/O) * 1/512 (ifft norm)
  const size_t bbase = (size_t)b * (FREQ_ * FRAMES_);
  const float* __restrict__ sr0 = sre + bbase;       // block-uniform base (SGPR)
  const float* __restrict__ si0 = sim + bbase;
  const int brev3[8] = {0, 4, 2, 6, 1, 5, 3, 7};

  // ---- batch-issue ALL 32 global loads first (memory-level parallelism) ----
  // 32-bit offsets: max index = fgc + 512*2048 < 2^21, so the compiler can use
  // s[base] + u32 voffset addressing.
  float xr1[8], xi1[8], xr2[8], xi2[8];
#pragma unroll
  for (int m = 0; m < 8; ++m) {
    const int i  = j + (m << 6);       // 0..511
    const int o1 = fgc + i * FRAMES_;
    const int o2 = fgc + (NH_ - i) * FRAMES_;
    xr1[m] = sr0[o1];
    xi1[m] = si0[o1];
    xr2[m] = sr0[o2];
    xi2[m] = si0[o2];
  }

  // ---- generate twiddle tables in LDS while loads are in flight ----
  {
    float s_, c_;
    if (t < 512) {
      __sincosf((float)t * (6.2831853071795864769f / 512.f), &s_, &c_);
      TW[t] = make_float2(c_, s_);
    } else {
      const int k = t - 512;
      __sincosf((float)k * (3.1415926535897932385f / 512.f), &s_, &c_);
      PRE[k] = make_float2(c_, s_);
    }
  }
  __syncthreads();

  // Fence: force all 32 loaded values live here (single vmcnt wait, latency
  // covered by the table gen + barrier above).
  KEEP8(xr1); KEEP8(xi1); KEEP8(xr2); KEEP8(xi2);

  // ---- pass 1: E/O fold + twiddle + radix-8 + b64 LDS write ----
  {
    float zr[8], zi[8];
#pragma unroll
    for (int m = 0; m < 8; ++m) {
      const int i = j + (m << 6);
      float a  = xr1[m], bi_ = xi1[m];
      float cr = xr2[m], di  = xi2[m];
      if (i == 0) { bi_ = 0.f; di = 0.f; }   // irfft ignores Im of bins 0,512
      const float Er = a + cr, Ei = bi_ - di;
      const float Dr = a - cr, Di = bi_ + di;
      const float2 w = PRE[i];               // e^{+2pi i * i /1024}
      const float Or = w.x * Dr - w.y * Di;
      const float Oi = w.x * Di + w.y * Dr;
      zr[m] = (Er - Oi) * scale;
      zi[m] = (Ei + Or) * scale;
    }
    idft8(zr, zi);
    float2* __restrict__ zrow = Z2 + f * ZSTR2 + j;
#pragma unroll
    for (int r = 0; r < 8; ++r) {
      const int mp = brev3[r];
      if (mp == 0) zrow[0] = make_float2(zr[r], zi[r]);
      else {
        const float2 w = TW[j * mp];         // W_512^{j*mp}
        zrow[mp << 6] = make_float2(zr[r] * w.x - zi[r] * w.y,
                                    zr[r] * w.y + zi[r] * w.x);
      }
    }
  }
  __syncthreads();

  // ---- pass 2: b64 LDS exchange + radix-8 + twiddle ----
  {
    const int pos = j & 7, blk = j >> 3;
    float2* __restrict__ zrow = Z2 + f * ZSTR2 + (blk << 6) + pos;
    float zr[8], zi[8];
#pragma unroll
    for (int m = 0; m < 8; ++m) {
      const float2 v = zrow[m << 3];
      zr[m] = v.x; zi[m] = v.y;
    }
    idft8(zr, zi);
#pragma unroll
    for (int r = 0; r < 8; ++r) {
      const int mp = brev3[r];
      if (mp == 0) zrow[0] = make_float2(zr[r], zi[r]);
      else {
        const float2 w = TW[(pos * mp) << 3];   // W_64^{pos*mp}
        zrow[mp << 3] = make_float2(zr[r] * w.x - zi[r] * w.y,
                                    zr[r] * w.y + zi[r] * w.x);
      }
    }
  }
  __syncthreads();

  // ---- pass 3: b64 read + radix-8 (final, twiddle-free outputs) ----
  float yr[8], yi[8];
  {
    const float2* __restrict__ zrow = Z2 + f * ZSTR2 + (j << 3);
#pragma unroll
    for (int m = 0; m < 8; ++m) {
      const float2 v = zrow[m];
      yr[m] = v.x; yi[m] = v.y;
    }
  }
  // prefetch window pairs (global, L1-hot) before the butterfly + barrier
  const int c = ((j & 7) << 3) + (j >> 3);        // Stockham output perm
  float2 wv[8];
  {
    const float2* __restrict__ win2 = (const float2*)win;
#pragma unroll
    for (int r = 0; r < 8; ++r) wv[r] = win2[(brev3[r] << 6) + c];
  }
  idft8(yr, yi);
  __syncthreads();                     // all Z reads done before XW overlay

  // ---- window + scatter to de-interleaved XW planes ----
  // time sample pair m: x[2m]=Re z[m], x[2m+1]=Im z[m]; m = brev3(r)*64 + c.
  float* __restrict__ XWe = lds;                    // [f][m] even samples (Re)
  float* __restrict__ XWo = lds + 16 * XWSTR;       // [f][m] odd samples  (Im)
  {
    float* __restrict__ er = XWe + f * XWSTR + c;
    float* __restrict__ od = XWo + f * XWSTR + c;
#pragma unroll
    for (int r = 0; r < 8; ++r) {
      const int mp = brev3[r];
      er[mp << 6] = yr[r] * wv[r].x;
      od[mp << 6] = yi[r] * wv[r].y;
    }
  }
  __syncthreads();

  // ---- overlap-add from LDS + envelope divide + coalesced float2 store ----
  // COLA: sum_j hann^2(p+256j) = 1.5 exactly -> invenv = 2/3 except near edges.
  float* __restrict__ outb = out + (size_t)b * T_OUT_;
#pragma unroll
  for (int rr = 0; rr < 2; ++rr) {
    const int idx = t + (rr << 10);    // 0..1535 used
    if (idx < 1536) {
      const int s = s0 + (idx << 1);
      if (s < T_OUT_) {
        const int u   = s + PAD_;
        const int fh  = u >> 8;
        const int me0 = (u & 255) >> 1;     // even-sample index within hop
        float vr = 0.f, vi = 0.f;
#pragma unroll
        for (int jj = 0; jj < 4; ++jj) {
          const int fl = fh - jj - f_base;  // 0..15 by construction
          const int a  = fl * XWSTR + me0 + (jj << 7);
          vr += XWe[a]; vi += XWo[a];
        }
        float ivx, ivy;
        if (u >= 768 && u <= T_OUT_ - 2) {  // u and u+1 both in full-overlap region
          ivx = 0.66666666667f; ivy = 0.66666666667f;
        } else {                            // edge WGs only (first/last column)
          float iv[2];
#pragma unroll
          for (int h = 0; h < 2; ++h) {
            const int uu  = u + h;
            const int fh2 = min(FRAMES_ - 1, uu >> 8);
            const int fl2 = (uu >= NFFT_) ? (((uu - NFFT_) >> 8) + 1) : 0;
            float e = 0.f;
            for (int ff = fl2; ff <= fh2; ++ff) {
              const float w = win[uu - (ff << 8)];
              e += w * w;
            }
            iv[h] = 1.0f / e;
          }
          ivx = iv[0]; ivy = iv[1];
        }
        *(float2*)(outb + s) = make_float2(vr * ivx, vi * ivy);
      }
    }
  }
}

extern "C" void kernel_launch(void* const* d_in, const int* in_sizes, int n_in,
                              void* d_out, int out_size, void* d_ws, size_t ws_size,
                              hipStream_t stream) {
  (void)in_sizes; (void)n_in; (void)out_size; (void)d_ws; (void)ws_size;
  const float* sre = (const float*)d_in[0];
  const float* sim = (const float*)d_in[1];
  const float* win = (const float*)d_in[2];
  float* out = (float*)d_out;
  k_fused<<<B_ * NCHUNK, 1024, 0, stream>>>(sre, sim, win, out);
}

// Round 3
// 189.329 us; speedup vs baseline: 1.0938x; 1.0938x over previous
//
#include <hip/hip_runtime.h>

// Fused Xcodec2 ISTFT: B=16, FREQ=513, FRAMES=2048, n_fft=1024, hop=256, win=1024
// out: [16, 1, 524288] fp32
//
// One-frame-per-wave version (barrier-free FFT):
//  - Spectra staged coalesced global -> frame-major LDS rows (float2 loads).
//  - Each wave runs one 512-pt complex inverse FFT (radix-8 Stockham, 3 reg
//    butterflies, 2 in-row LDS exchanges) entirely within its own LDS row:
//    no __syncthreads between FFT passes, only wave-local lgkmcnt fences.
//    Z slot addresses XOR-swizzled (a = s ^ (s>>3)) for bank-conflict-free
//    reads in all 3 passes.
//  - Windowed frame (even|odd planes) overwrites the wave's own row; one
//    barrier before the overlap-add.
//  - COLA identity: sum_j hann^2(p+256j) = 1.5 -> invenv = 2/3 except edges.
//  - 2 barriers total (was 5).

#define B_      16
#define FREQ_   513
#define FRAMES_ 2048
#define HOP_    256
#define NH_     512
#define PAD_    384
#define T_OUT_  524288
#define HPW     12           // useful hops per WG
#define SPW     3072         // output samples per WG
#define NCHUNK  171          // ceil(T_OUT/SPW)

#define FS2     515          // float2 stride of one frame row in S
#define TWOFF   8240         // float2 offset of TW   (16*515)
#define PREOFF  8752         // float2 offset of PRE
#define WINOFF  9264         // float2 offset of WIN
#define LDS2N   9776         // total float2 (78,208 B -> 2 WG/CU)

#define LGKM_SYNC() asm volatile("s_waitcnt lgkmcnt(0)" ::: "memory")

// 8-point inverse DFT (sign +i), DIF, in-place; output slot r holds y[brev3(r)].
__device__ __forceinline__ void idft8(float* zr, float* zi) {
  const float C = 0.70710678118654752f;
  float tr, ti;
  tr = zr[0]-zr[4]; ti = zi[0]-zi[4]; zr[0]+=zr[4]; zi[0]+=zi[4]; zr[4]=tr;         zi[4]=ti;
  tr = zr[1]-zr[5]; ti = zi[1]-zi[5]; zr[1]+=zr[5]; zi[1]+=zi[5]; zr[5]=C*(tr-ti);  zi[5]=C*(tr+ti);
  tr = zr[2]-zr[6]; ti = zi[2]-zi[6]; zr[2]+=zr[6]; zi[2]+=zi[6]; zr[6]=-ti;        zi[6]=tr;
  tr = zr[3]-zr[7]; ti = zi[3]-zi[7]; zr[3]+=zr[7]; zi[3]+=zi[7]; zr[7]=-C*(tr+ti); zi[7]=C*(tr-ti);
  tr = zr[0]-zr[2]; ti = zi[0]-zi[2]; zr[0]+=zr[2]; zi[0]+=zi[2]; zr[2]=tr;  zi[2]=ti;
  tr = zr[1]-zr[3]; ti = zi[1]-zi[3]; zr[1]+=zr[3]; zi[1]+=zi[3]; zr[3]=-ti; zi[3]=tr;
  tr = zr[4]-zr[6]; ti = zi[4]-zi[6]; zr[4]+=zr[6]; zi[4]+=zi[6]; zr[6]=tr;  zi[6]=ti;
  tr = zr[5]-zr[7]; ti = zi[5]-zi[7]; zr[5]+=zr[7]; zi[5]+=zi[7]; zr[7]=-ti; zi[7]=tr;
  tr = zr[0]-zr[1]; ti = zi[0]-zi[1]; zr[0]+=zr[1]; zi[0]+=zi[1]; zr[1]=tr; zi[1]=ti;
  tr = zr[2]-zr[3]; ti = zi[2]-zi[3]; zr[2]+=zr[3]; zi[2]+=zi[3]; zr[3]=tr; zi[3]=ti;
  tr = zr[4]-zr[5]; ti = zi[4]-zi[5]; zr[4]+=zr[5]; zi[4]+=zi[5]; zr[5]=tr; zi[5]=ti;
  tr = zr[6]-zr[7]; ti = zi[6]-zi[7]; zr[6]+=zr[7]; zi[6]+=zi[7]; zr[7]=tr; zi[7]=ti;
}

__global__ __launch_bounds__(1024, 8) void k_fused(
    const float* __restrict__ sre, const float* __restrict__ sim,
    const float* __restrict__ win, float* __restrict__ out) {
  __shared__ __align__(16) float2 lds2[LDS2N];
  float2* S    = lds2;                 // 16 frame rows, stride FS2
  float2* TW2  = lds2 + TWOFF;         // W_512^k, k=0..511
  float2* PRE2 = lds2 + PREOFF;        // e^{+i pi k/512}, k=0..511
  float2* WIN2 = lds2 + WINOFF;        // (win[2m], win[2m+1])

  const int t   = threadIdx.x;
  const int b   = blockIdx.x & 15;
  const int wgq = blockIdx.x >> 4;
  const int f_base = HPW * wgq - 2;    // even
  const int s0     = SPW * wgq;

  // ---- stage spectra: coalesced float2 global loads -> frame-major rows ----
  {
    const float2* __restrict__ sre2 = (const float2*)sre + (size_t)b * (FREQ_ * 1024);
    const float2* __restrict__ sim2 = (const float2*)sim + (size_t)b * (FREQ_ * 1024);
    const int wp  = t & 7;                       // frame-pair slot
    const int fg0 = f_base + (wp << 1);          // even
    const int cb2 = (min(max(fg0, 0), FRAMES_ - 2)) >> 1;  // clamped float2 col
    const int row0 = t >> 3;
#pragma unroll
    for (int k = 0; k < 4; ++k) {
      const int row = row0 + (k << 7);           // 0..511
      const int a   = (row << 10) + cb2;
      const float2 re2 = sre2[a];
      const float2 im2 = sim2[a];
      S[(wp << 1) * FS2 + row]       = make_float2(re2.x, im2.x);
      S[((wp << 1) + 1) * FS2 + row] = make_float2(re2.y, im2.y);
    }
    if (t < 8) {                                 // row 512 tail
      const int a = (512 << 10) + cb2;
      const float2 re2 = sre2[a];
      const float2 im2 = sim2[a];
      S[(wp << 1) * FS2 + 512]       = make_float2(re2.x, im2.x);
      S[((wp << 1) + 1) * FS2 + 512] = make_float2(re2.y, im2.y);
    }
  }

  // ---- tables (overlapped with staging-load latency) ----
  if (t < 512) {
    float s_, c_;
    __sincosf((float)t * (6.2831853071795864769f / 512.f), &s_, &c_);
    TW2[t]  = make_float2(c_, s_);
    WIN2[t] = ((const float2*)win)[t];
  } else {
    const int k = t - 512;
    float s_, c_;
    __sincosf((float)k * (3.1415926535897932385f / 512.f), &s_, &c_);
    PRE2[k] = make_float2(c_, s_);
  }
  __syncthreads();                               // barrier A

  // ================= per-wave FFT (no barriers) =================
  const int w  = t >> 6;                 // wave id = frame slot
  const int j  = t & 63;                 // lane = butterfly index
  const int fg = f_base + w;
  const float scale = (fg >= 0 && fg < FRAMES_) ? (0.5f / 512.0f) : 0.0f;
  float2* Zs = S + w * FS2;              // this wave's private row
  const int brev3[8] = {0, 4, 2, 6, 1, 5, 3, 7};

  // load + E/O fold
  float2 x1[8], x2[8];
#pragma unroll
  for (int m = 0; m < 8; ++m) {
    x1[m] = Zs[j + (m << 6)];
    x2[m] = Zs[512 - j - (m << 6)];
  }
  float zr[8], zi[8];
#pragma unroll
  for (int m = 0; m < 8; ++m) {
    const int i = j + (m << 6);
    float ar = x1[m].x, ai = x1[m].y;
    float br = x2[m].x, bi = x2[m].y;
    if (i == 0) { ai = 0.f; bi = 0.f; }  // irfft ignores Im of bins 0,512
    const float Er = ar + br, Ei = ai - bi;
    const float Dr = ar - br, Di = ai + bi;
    const float2 pw = PRE2[i];           // e^{+2pi i * i /1024}
    const float Or = pw.x * Dr - pw.y * Di;
    const float Oi = pw.x * Di + pw.y * Dr;
    zr[m] = (Er - Oi) * scale;
    zi[m] = (Ei + Or) * scale;
  }
  idft8(zr, zi);
  // pass 1 write (swizzle a = s ^ (s>>3); s = mp*64 + j)
  const int jx = j ^ (j >> 3);
#pragma unroll
  for (int r = 0; r < 8; ++r) {
    const int mp = brev3[r];
    const int a  = (mp << 6) | (jx ^ (mp << 3));
    if (mp == 0) Zs[a] = make_float2(zr[r], zi[r]);
    else {
      const float2 tw = TW2[j * mp];     // W_512^{j*mp}
      Zs[a] = make_float2(zr[r]*tw.x - zi[r]*tw.y, zr[r]*tw.y + zi[r]*tw.x);
    }
  }
  LGKM_SYNC();
  // pass 2 (s_read = blk*64 + m*8 + pos; s_write = blk*64 + mp*8 + pos)
  {
    const int pos = j & 7, blk = j >> 3;
#pragma unroll
    for (int m = 0; m < 8; ++m) {
      const int a = (blk << 6) | (((m << 3) | pos) ^ ((blk << 3) | m));
      const float2 v = Zs[a];
      zr[m] = v.x; zi[m] = v.y;
    }
    idft8(zr, zi);
#pragma unroll
    for (int r = 0; r < 8; ++r) {
      const int mp = brev3[r];
      const int a  = (blk << 6) | (((mp << 3) | pos) ^ ((blk << 3) | mp));
      if (mp == 0) Zs[a] = make_float2(zr[r], zi[r]);
      else {
        const float2 tw = TW2[(pos * mp) << 3];   // W_64^{pos*mp}
        Zs[a] = make_float2(zr[r]*tw.x - zi[r]*tw.y, zr[r]*tw.y + zi[r]*tw.x);
      }
    }
  }
  LGKM_SYNC();
  // pass 3 (s = j*8 + m -> a = ((j<<3)^j) ^ m), final butterfly, twiddle-free
  float yr[8], yi[8];
  {
    const int b3 = (j << 3) ^ j;
#pragma unroll
    for (int m = 0; m < 8; ++m) {
      const float2 v = Zs[b3 ^ m];
      yr[m] = v.x; yi[m] = v.y;
    }
  }
  idft8(yr, yi);
  // window + overwrite own row as [even 512 | odd 512] floats
  // time sample pair mt: x[2mt]=Re z[mt], x[2mt+1]=Im z[mt]; mt = brev3(r)*64+c
  {
    const int c = ((j & 7) << 3) | (j >> 3);      // Stockham output perm
    float* XWrow = (float*)Zs;
#pragma unroll
    for (int r = 0; r < 8; ++r) {
      const int mp = brev3[r];
      const int mt = (mp << 6) | c;
      const float2 wv = WIN2[mt];
      XWrow[mt]       = yr[r] * wv.x;
      XWrow[512 + mt] = yi[r] * wv.y;
    }
  }
  __syncthreads();                               // barrier B

  // ---- overlap-add + envelope divide + coalesced float2 store ----
  // COLA: sum_j hann^2(p+256j) = 1.5 exactly -> invenv = 2/3 except edges.
  float* __restrict__ outb = out + (size_t)b * T_OUT_;
  const float* ldsf = (const float*)lds2;
#pragma unroll
  for (int rr = 0; rr < 2; ++rr) {
    const int idx = t + (rr << 10);    // 0..1535 used
    if (idx < 1536) {
      const int s = s0 + (idx << 1);
      if (s < T_OUT_) {
        const int u   = s + PAD_;
        const int fh  = u >> 8;
        const int me0 = (u & 255) >> 1;     // even-sample index within hop
        float vr = 0.f, vi = 0.f;
#pragma unroll
        for (int jj = 0; jj < 4; ++jj) {
          const int fl = fh - jj - f_base;  // 0..15 by construction
          const int af = fl * (FS2 * 2) + (jj << 7) + me0;
          vr += ldsf[af];
          vi += ldsf[af + 512];
        }
        float ivx, ivy;
        if (u >= 768 && u <= T_OUT_ - 2) {  // full-overlap interior
          ivx = 0.66666666667f; ivy = 0.66666666667f;
        } else {                            // edge samples only
          float iv[2];
#pragma unroll
          for (int h = 0; h < 2; ++h) {
            const int uu  = u + h;
            const int fh2 = min(FRAMES_ - 1, uu >> 8);
            const int fl2 = (uu >= 1024) ? (((uu - 1024) >> 8) + 1) : 0;
            float e = 0.f;
            for (int ff = fl2; ff <= fh2; ++ff) {
              const float ww = win[uu - (ff << 8)];
              e += ww * ww;
            }
            iv[h] = 1.0f / e;
          }
          ivx = iv[0]; ivy = iv[1];
        }
        *(float2*)(outb + s) = make_float2(vr * ivx, vi * ivy);
      }
    }
  }
}

extern "C" void kernel_launch(void* const* d_in, const int* in_sizes, int n_in,
                              void* d_out, int out_size, void* d_ws, size_t ws_size,
                              hipStream_t stream) {
  (void)in_sizes; (void)n_in; (void)out_size; (void)d_ws; (void)ws_size;
  const float* sre = (const float*)d_in[0];
  const float* sim = (const float*)d_in[1];
  const float* win = (const float*)d_in[2];
  float* out = (float*)d_out;
  k_fused<<<B_ * NCHUNK, 1024, 0, stream>>>(sre, sim, win, out);
}